// Round 11
// baseline (199.084 us; speedup 1.0000x reference)
//
#include <hip/hip_runtime.h>
#include <hip/hip_bf16.h>

// Swin block fully fused, bf16 MFMA. B=64, H=W=56, C=96, nh=3, d=32, WS=7, SS=3, N=49, nW=64.
// Round 11: pipelined weight staging (issue -> compute -> barrier, ping-pong bufA/bufB in
// dead K/V regions), QK-all-heads-first to free K early, bias+mask via MFMA C-in,
// softmax without max-subtraction (scores bounded, masked lanes exp->0).
typedef __attribute__((ext_vector_type(8))) short short8;  // 8 bf16 = one A/B frag
typedef __attribute__((ext_vector_type(4))) float f32x4;   // C/D frag

constexpr int HW = 56;

// ---- LDS pool (bf16 elements). Frag-read bases 16B-aligned. ----
constexpr int SR    = 104;             // row stride for [64][96] token-major buffers
constexpr int SVT   = 200;             // row stride for vT [32][3*64]
constexpr int OFF_X = 0;               // [64][SR]: xln -> P (own row) -> fc1 h (own row)
constexpr int OFF_Q = 64 * SR;         // [64][SR]: q -> attn-out (own row) -> yn (own row)
constexpr int OFF_K = 2 * 64 * SR;     // [64][SR]: k ; after QK: stage bufA (4608 sh = 9216B)
constexpr int OFF_V = 3 * 64 * SR;     // [32][SVT]: v^T ; after PV: stage bufB
constexpr int POOLN = OFF_V + 32 * SVT;  // 26368 shorts = 52736 B -> 3 blocks/CU

// ---- d_ws layout (bf16), frag-major: [(set)*512 + lane*8 + j], set = tile*3+s ----
constexpr int WQKV  = 0;               // 18 tiles
constexpr int WPROJ = 27648;           // 6 tiles (18 sets; h0 = sets 0..8, h1 = 9..17)
constexpr int WFC1  = 36864;           // 24 tiles, chunk-major: chunk cn = 18 sets
constexpr int WFC2  = 73728;           // 24 tiles, chunk-major
constexpr int WTOT  = 110592;          // *2B = 221184 bytes

__device__ __forceinline__ ushort bfc(float f) {
  union { __hip_bfloat16 h; ushort u; } v;
  v.h = __float2bfloat16(f);
  return v.u;
}
__device__ __forceinline__ uint pk2(float a, float b) {
  union { __hip_bfloat162 h2; uint u; } v;
  v.h2 = __float22bfloat162_rn(make_float2(a, b));
  return v.u;
}
__device__ __forceinline__ void st4(short* p, float a, float b, float c, float d) {
  uint2 u; u.x = pk2(a, b); u.y = pk2(c, d);
  *(uint2*)p = u;
}
__device__ __forceinline__ short8 ldw8(const float* p) {
  float4 a = *(const float4*)p;
  float4 b = *(const float4*)(p + 4);
  short8 r;
  r[0] = (short)bfc(a.x); r[1] = (short)bfc(a.y); r[2] = (short)bfc(a.z); r[3] = (short)bfc(a.w);
  r[4] = (short)bfc(b.x); r[5] = (short)bfc(b.y); r[6] = (short)bfc(b.z); r[7] = (short)bfc(b.w);
  return r;
}
template<bool PRE>
__device__ __forceinline__ short8 wfrag(const short* wsb, int ts, int lane, const float* fsrc) {
  if constexpr (PRE) return *(const short8*)&wsb[(ts << 9) + lane * 8];
  else               return ldw8(fsrc);
}
// GELU sigmoid form: x * sigma(1.702 x)
__device__ __forceinline__ float gelu(float v) {
  return v / (1.0f + __expf(-1.702f * v));
}
// stage 9 sets (9216B) global->LDS, wave-split (wave w takes sets w, w+4, w+8)
__device__ __forceinline__ void stage9(const short* g0, short* l0, int wv, int lane) {
  #pragma unroll
  for (int s4 = 0; s4 < 3; ++s4) {
    int s = wv + 4 * s4;
    if (s < 9)
      __builtin_amdgcn_global_load_lds((const unsigned int*)(g0 + (s << 9) + lane * 8),
                                       (unsigned int*)(l0 + (s << 9)), 16, 0, 0);
  }
}

// one-shot weight conversion f32 -> bf16, frag-major (same layout as round 10)
__global__ __launch_bounds__(256) void cvt_weights(
    const float* __restrict__ qkv_w, const float* __restrict__ proj_w,
    const float* __restrict__ fc1_w, const float* __restrict__ fc2_w,
    short* __restrict__ ws)
{
  int idx = blockIdx.x * 256 + threadIdx.x;
  if (idx >= WTOT) return;
  int j = idx & 7, lane = (idx >> 3) & 63;
  int cl = lane & 15;
  int g  = 8 * (lane >> 4) + j;
  float v;
  if (idx < WPROJ) {
    int ts = idx >> 9; int tile = ts / 3, s = ts - 3 * tile;
    v = qkv_w[(size_t)(16 * tile + cl) * 96 + 32 * s + g];
  } else if (idx < WFC1) {
    int ts = (idx - WPROJ) >> 9; int tile = ts / 3, s = ts - 3 * tile;
    v = proj_w[(size_t)(16 * tile + cl) * 96 + 32 * s + g];
  } else if (idx < WFC2) {
    int ts = (idx - WFC1) >> 9; int T = ts / 3, s = ts - 3 * T;
    int cn = T / 6, nt = T - 6 * cn;
    v = fc1_w[(size_t)(96 * cn + 16 * nt + cl) * 96 + 32 * s + g];
  } else {
    int ts = (idx - WFC2) >> 9; int T = ts / 3, s = ts - 3 * T;
    int cn = T / 6, nt = T - 6 * cn;
    v = fc2_w[(size_t)(16 * nt + cl) * 384 + 96 * cn + 32 * s + g];
  }
  ws[idx] = (short)bfc(v);
}

template<bool PRE>
__global__ __launch_bounds__(256, 3) void swin_mfma_kernel(
    const float* __restrict__ x,          // [B,3136,96]
    const float* __restrict__ attn_mask,  // [64,49,49]
    const int*   __restrict__ rel_index,  // [2401]
    const float* __restrict__ n1g, const float* __restrict__ n1b,
    const float* __restrict__ qkv_w, const float* __restrict__ qkv_b,
    const float* __restrict__ rel_tab,    // [169,3]
    const float* __restrict__ proj_w, const float* __restrict__ proj_b,
    const float* __restrict__ n2g, const float* __restrict__ n2b,
    const float* __restrict__ fc1_w, const float* __restrict__ fc1_b,
    const float* __restrict__ fc2_w, const float* __restrict__ fc2_b,
    const short* __restrict__ wsw,
    float* __restrict__ out)              // [B,3136,96]
{
  __shared__ alignas(16) short pool[POOLN];
  short* bufA = (short*)&pool[OFF_K];
  short* bufB = (short*)&pool[OFF_V];

  const int tid  = threadIdx.x;
  const int wv   = tid >> 6;          // wave id = token 16-strip owner
  const int lane = tid & 63;
  const int ln   = lane & 15;
  const int gq   = lane >> 4;
  const int bw   = blockIdx.x;
  const int b    = bw >> 6, widx = bw & 63;
  const int wr   = widx >> 3, wc = widx & 7;

  const f32x4 zf = {0.f, 0.f, 0.f, 0.f};
  const int qq = 16 * wv + ln;        // this thread's token row

  auto gbase = [&](int n) -> size_t {
    int i = n / 7, j = n - 7 * i;
    int h = wr * 7 + i + 3; if (h >= HW) h -= HW;   // roll(-3)
    int w = wc * 7 + j + 3; if (w >= HW) w -= HW;
    return ((size_t)b * (HW * HW) + (size_t)h * HW + w) * 96;
  };
  const size_t obase = gbase(qq < 49 ? qq : 48);

  // ---- phase 1: token-per-thread-column load + LN1 -> xln; raw x kept in VGPRs ----
  float xraw[6][4];
  {
    if (qq < 49) {
      const float* xr = x + obase;
      #pragma unroll
      for (int nt = 0; nt < 6; ++nt) {
        float4 v = *(const float4*)&xr[16 * nt + 4 * gq];
        xraw[nt][0] = v.x; xraw[nt][1] = v.y; xraw[nt][2] = v.z; xraw[nt][3] = v.w;
      }
    } else {
      #pragma unroll
      for (int nt = 0; nt < 6; ++nt)
        xraw[nt][0] = xraw[nt][1] = xraw[nt][2] = xraw[nt][3] = 0.f;
    }
    float s1 = 0.f, s2 = 0.f;
    #pragma unroll
    for (int nt = 0; nt < 6; ++nt)
      #pragma unroll
      for (int r = 0; r < 4; ++r) { s1 += xraw[nt][r]; s2 += xraw[nt][r] * xraw[nt][r]; }
    s1 += __shfl_xor(s1, 16, 64); s1 += __shfl_xor(s1, 32, 64);
    s2 += __shfl_xor(s2, 16, 64); s2 += __shfl_xor(s2, 32, 64);
    float mean = s1 * (1.f / 96.f);
    float inv  = rsqrtf(s2 * (1.f / 96.f) - mean * mean + 1e-5f);
    #pragma unroll
    for (int nt = 0; nt < 6; ++nt) {
      float4 g4 = *(const float4*)&n1g[16 * nt + 4 * gq];
      float4 b4 = *(const float4*)&n1b[16 * nt + 4 * gq];
      st4(&pool[OFF_X + qq * SR + 16 * nt + 4 * gq],
          (xraw[nt][0] - mean) * inv * g4.x + b4.x,
          (xraw[nt][1] - mean) * inv * g4.y + b4.y,
          (xraw[nt][2] - mean) * inv * g4.z + b4.z,
          (xraw[nt][3] - mean) * inv * g4.w + b4.w);
    }
  }
  __syncthreads();

  // ---- phase 2: QKV + combined bias preload (rel_tab gather hidden under QKV) ----
  f32x4 biasc[3][4];   // rel_bias + mask per head, C-in layout D[key][q]
  {
    int qc = qq < 49 ? qq : 48;
    #pragma unroll
    for (int nt = 0; nt < 4; ++nt)
      #pragma unroll
      for (int r = 0; r < 4; ++r) {
        int key = 16 * nt + 4 * gq + r;
        if (key < 49) {
          int qk = qc * 49 + key;
          int idx = rel_index[qk];
          float m = attn_mask[(size_t)widx * 2401 + qk];
          biasc[0][nt][r] = rel_tab[idx * 3 + 0] + m;
          biasc[1][nt][r] = rel_tab[idx * 3 + 1] + m;
          biasc[2][nt][r] = rel_tab[idx * 3 + 2] + m;
        } else {
          biasc[0][nt][r] = -1e30f;
          biasc[1][nt][r] = -1e30f;
          biasc[2][nt][r] = -1e30f;
        }
      }
  }
  {
    short8 af[3][4];
    #pragma unroll
    for (int s = 0; s < 3; ++s)
      #pragma unroll
      for (int m = 0; m < 4; ++m)
        af[s][m] = *(const short8*)&pool[OFF_X + (16 * m + ln) * SR + 32 * s + 8 * gq];

    for (int t = wv; t < 18; t += 4) {
      short8 wf[3];
      #pragma unroll
      for (int s = 0; s < 3; ++s)
        wf[s] = wfrag<PRE>(wsw + WQKV, t * 3 + s, lane,
                           qkv_w + (size_t)(16 * t + ln) * 96 + 32 * s + 8 * gq);
      int which = t / 6;               // 0=q 1=k 2=v
      if (which == 2) {
        int d  = 16 * (t - 12) + ln;
        float bv = qkv_b[192 + d];
        int dd = d & 31, hh = d >> 5;
        #pragma unroll
        for (int m = 0; m < 4; ++m) {
          f32x4 acc = zf;
          #pragma unroll
          for (int s = 0; s < 3; ++s)
            acc = __builtin_amdgcn_mfma_f32_16x16x32_bf16(af[s][m], wf[s], acc, 0, 0, 0);
          st4(&pool[OFF_V + dd * SVT + hh * 64 + 16 * m + 4 * gq],
              acc[0] + bv, acc[1] + bv, acc[2] + bv, acc[3] + bv);
        }
      } else {
        float4 b4 = *(const float4*)&qkv_b[16 * t + 4 * gq];
        #pragma unroll
        for (int m = 0; m < 4; ++m) {
          f32x4 acc = zf;
          #pragma unroll
          for (int s = 0; s < 3; ++s)
            acc = __builtin_amdgcn_mfma_f32_16x16x32_bf16(wf[s], af[s][m], acc, 0, 0, 0);
          int tok = 16 * m + ln;
          float v0 = acc[0] + b4.x, v1 = acc[1] + b4.y, v2 = acc[2] + b4.z, v3 = acc[3] + b4.w;
          if (which == 0) {
            const float sc_ = 0.17677669529663687f;
            st4(&pool[OFF_Q + tok * SR + 16 * t + 4 * gq], v0 * sc_, v1 * sc_, v2 * sc_, v3 * sc_);
          } else {
            st4(&pool[OFF_K + tok * SR + 16 * (t - 6) + 4 * gq], v0, v1, v2, v3);
          }
        }
      }
    }
  }
  __syncthreads();

  // ---- phase 3: QK^T for ALL heads (bias+mask via C-in), then K is dead ----
  f32x4 sc[3][4];
  #pragma unroll
  for (int h = 0; h < 3; ++h) {
    short8 bq = *(const short8*)&pool[OFF_Q + qq * SR + h * 32 + 8 * gq];
    #pragma unroll
    for (int nt = 0; nt < 4; ++nt) {
      short8 ak = *(const short8*)&pool[OFF_K + (16 * nt + ln) * SR + h * 32 + 8 * gq];
      sc[h][nt] = __builtin_amdgcn_mfma_f32_16x16x32_bf16(ak, bq, biasc[h][nt], 0, 0, 0);
    }
  }
  __syncthreads();   // K dead everywhere -> bufA usable

  // ---- phase 4: stage proj-h0 -> bufA || softmax (no max-sub) + PV + AO writes ----
  if constexpr (PRE) stage9(wsw + WPROJ, bufA, wv, lane);
  #pragma unroll
  for (int h = 0; h < 3; ++h) {
    float pv[4][4];
    float sum = 0.f;
    #pragma unroll
    for (int nt = 0; nt < 4; ++nt)
      #pragma unroll
      for (int r = 0; r < 4; ++r) { pv[nt][r] = __expf(sc[h][nt][r]); sum += pv[nt][r]; }
    sum += __shfl_xor(sum, 16, 64);
    sum += __shfl_xor(sum, 32, 64);
    float inv = 1.f / sum;
    #pragma unroll
    for (int nt = 0; nt < 4; ++nt)
      st4(&pool[OFF_X + qq * SR + 16 * nt + 4 * gq],
          pv[nt][0] * inv, pv[nt][1] * inv, pv[nt][2] * inv, pv[nt][3] * inv);

    short8 bp0 = *(const short8*)&pool[OFF_X + qq * SR + 8 * gq];
    short8 bp1 = *(const short8*)&pool[OFF_X + qq * SR + 32 + 8 * gq];
    #pragma unroll
    for (int dt = 0; dt < 2; ++dt) {
      short8 av0 = *(const short8*)&pool[OFF_V + (16 * dt + ln) * SVT + h * 64 + 8 * gq];
      short8 av1 = *(const short8*)&pool[OFF_V + (16 * dt + ln) * SVT + h * 64 + 32 + 8 * gq];
      f32x4 o = __builtin_amdgcn_mfma_f32_16x16x32_bf16(av0, bp0, zf, 0, 0, 0);
      o = __builtin_amdgcn_mfma_f32_16x16x32_bf16(av1, bp1, o, 0, 0, 0);
      st4(&pool[OFF_Q + qq * SR + h * 32 + 16 * dt + 4 * gq], o[0], o[1], o[2], o[3]);
    }
  }
  short8 ao[3];
  #pragma unroll
  for (int s = 0; s < 3; ++s)
    ao[s] = *(const short8*)&pool[OFF_Q + qq * SR + 32 * s + 8 * gq];
  __syncthreads();   // V dead; bufA (proj-h0) landed

  // ---- phase 5: stage proj-h1 -> bufB || proj nt 0..2 ----
  if constexpr (PRE) stage9(wsw + WPROJ + 9 * 512, bufB, wv, lane);
  float y[6][4];
  #pragma unroll
  for (int nt = 0; nt < 3; ++nt) {
    f32x4 acc = zf;
    #pragma unroll
    for (int s = 0; s < 3; ++s) {
      short8 wfr = PRE ? *(const short8*)&bufA[(nt * 3 + s) * 512 + lane * 8]
                       : ldw8(proj_w + (size_t)(16 * nt + ln) * 96 + 32 * s + 8 * gq);
      acc = __builtin_amdgcn_mfma_f32_16x16x32_bf16(wfr, ao[s], acc, 0, 0, 0);
    }
    float4 pb = *(const float4*)&proj_b[16 * nt + 4 * gq];
    y[nt][0] = acc[0] + pb.x + xraw[nt][0];
    y[nt][1] = acc[1] + pb.y + xraw[nt][1];
    y[nt][2] = acc[2] + pb.z + xraw[nt][2];
    y[nt][3] = acc[3] + pb.w + xraw[nt][3];
  }
  __syncthreads();   // bufB (proj-h1) landed; bufA reads done

  // ---- phase 6: stage fc1c0h0 -> bufA || proj nt 3..5 + LN2 -> yn -> ay frags ----
  if constexpr (PRE) stage9(wsw + WFC1, bufA, wv, lane);
  #pragma unroll
  for (int nt = 3; nt < 6; ++nt) {
    f32x4 acc = zf;
    #pragma unroll
    for (int s = 0; s < 3; ++s) {
      short8 wfr = PRE ? *(const short8*)&bufB[((nt - 3) * 3 + s) * 512 + lane * 8]
                       : ldw8(proj_w + (size_t)(16 * nt + ln) * 96 + 32 * s + 8 * gq);
      acc = __builtin_amdgcn_mfma_f32_16x16x32_bf16(wfr, ao[s], acc, 0, 0, 0);
    }
    float4 pb = *(const float4*)&proj_b[16 * nt + 4 * gq];
    y[nt][0] = acc[0] + pb.x + xraw[nt][0];
    y[nt][1] = acc[1] + pb.y + xraw[nt][1];
    y[nt][2] = acc[2] + pb.z + xraw[nt][2];
    y[nt][3] = acc[3] + pb.w + xraw[nt][3];
  }
  {
    float s1 = 0.f, s2 = 0.f;
    #pragma unroll
    for (int nt = 0; nt < 6; ++nt)
      #pragma unroll
      for (int r = 0; r < 4; ++r) { s1 += y[nt][r]; s2 += y[nt][r] * y[nt][r]; }
    s1 += __shfl_xor(s1, 16, 64); s1 += __shfl_xor(s1, 32, 64);
    s2 += __shfl_xor(s2, 16, 64); s2 += __shfl_xor(s2, 32, 64);
    float mean = s1 * (1.f / 96.f);
    float inv  = rsqrtf(s2 * (1.f / 96.f) - mean * mean + 1e-5f);
    #pragma unroll
    for (int nt = 0; nt < 6; ++nt) {
      float4 g4 = *(const float4*)&n2g[16 * nt + 4 * gq];
      float4 b4 = *(const float4*)&n2b[16 * nt + 4 * gq];
      st4(&pool[OFF_Q + qq * SR + 16 * nt + 4 * gq],
          (y[nt][0] - mean) * inv * g4.x + b4.x,
          (y[nt][1] - mean) * inv * g4.y + b4.y,
          (y[nt][2] - mean) * inv * g4.z + b4.z,
          (y[nt][3] - mean) * inv * g4.w + b4.w);
    }
  }
  short8 ay[3];
  #pragma unroll
  for (int s = 0; s < 3; ++s)
    ay[s] = *(const short8*)&pool[OFF_Q + qq * SR + 32 * s + 8 * gq];
  __syncthreads();   // bufA (fc1c0h0) landed; bufB reads done

  // ---- phase 7: MLP, 4 chunks x 4 pipelined half-stages ----
  f32x4 accO[6] = {zf, zf, zf, zf, zf, zf};
  for (int cn = 0; cn < 4; ++cn) {
    // (a) stage fc1.cn.h1 -> bufB || fc1 nt 0..2 from bufA
    if constexpr (PRE) stage9(wsw + WFC1 + (cn * 18 + 9) * 512, bufB, wv, lane);
    #pragma unroll
    for (int nt = 0; nt < 3; ++nt) {
      f32x4 acc = zf;
      #pragma unroll
      for (int s = 0; s < 3; ++s) {
        short8 wfr = PRE ? *(const short8*)&bufA[(nt * 3 + s) * 512 + lane * 8]
                         : ldw8(fc1_w + (size_t)(96 * cn + 16 * nt + ln) * 96 + 32 * s + 8 * gq);
        acc = __builtin_amdgcn_mfma_f32_16x16x32_bf16(wfr, ay[s], acc, 0, 0, 0);
      }
      float4 b1 = *(const float4*)&fc1_b[96 * cn + 16 * nt + 4 * gq];
      st4(&pool[OFF_X + qq * SR + 16 * nt + 4 * gq],
          gelu(acc[0] + b1.x), gelu(acc[1] + b1.y),
          gelu(acc[2] + b1.z), gelu(acc[3] + b1.w));
    }
    __syncthreads();
    // (b) stage fc2.cn.h0 -> bufA || fc1 nt 3..5 from bufB; then ah frags
    if constexpr (PRE) stage9(wsw + WFC2 + (cn * 18) * 512, bufA, wv, lane);
    #pragma unroll
    for (int nt = 3; nt < 6; ++nt) {
      f32x4 acc = zf;
      #pragma unroll
      for (int s = 0; s < 3; ++s) {
        short8 wfr = PRE ? *(const short8*)&bufB[((nt - 3) * 3 + s) * 512 + lane * 8]
                         : ldw8(fc1_w + (size_t)(96 * cn + 16 * nt + ln) * 96 + 32 * s + 8 * gq);
        acc = __builtin_amdgcn_mfma_f32_16x16x32_bf16(wfr, ay[s], acc, 0, 0, 0);
      }
      float4 b1 = *(const float4*)&fc1_b[96 * cn + 16 * nt + 4 * gq];
      st4(&pool[OFF_X + qq * SR + 16 * nt + 4 * gq],
          gelu(acc[0] + b1.x), gelu(acc[1] + b1.y),
          gelu(acc[2] + b1.z), gelu(acc[3] + b1.w));
    }
    short8 ah[3];
    #pragma unroll
    for (int s = 0; s < 3; ++s)
      ah[s] = *(const short8*)&pool[OFF_X + qq * SR + 32 * s + 8 * gq];
    __syncthreads();
    // (c) stage fc2.cn.h1 -> bufB || fc2 nt 0..2 from bufA
    if constexpr (PRE) stage9(wsw + WFC2 + (cn * 18 + 9) * 512, bufB, wv, lane);
    #pragma unroll
    for (int nt = 0; nt < 3; ++nt) {
      #pragma unroll
      for (int s = 0; s < 3; ++s) {
        short8 wfr = PRE ? *(const short8*)&bufA[(nt * 3 + s) * 512 + lane * 8]
                         : ldw8(fc2_w + (size_t)(16 * nt + ln) * 384 + 96 * cn + 32 * s + 8 * gq);
        accO[nt] = __builtin_amdgcn_mfma_f32_16x16x32_bf16(wfr, ah[s], accO[nt], 0, 0, 0);
      }
    }
    __syncthreads();
    // (d) stage next fc1.(cn+1).h0 -> bufA || fc2 nt 3..5 from bufB
    if constexpr (PRE) { if (cn < 3) stage9(wsw + WFC1 + ((cn + 1) * 18) * 512, bufA, wv, lane); }
    #pragma unroll
    for (int nt = 3; nt < 6; ++nt) {
      #pragma unroll
      for (int s = 0; s < 3; ++s) {
        short8 wfr = PRE ? *(const short8*)&bufB[((nt - 3) * 3 + s) * 512 + lane * 8]
                         : ldw8(fc2_w + (size_t)(16 * nt + ln) * 384 + 96 * cn + 32 * s + 8 * gq);
        accO[nt] = __builtin_amdgcn_mfma_f32_16x16x32_bf16(wfr, ah[s], accO[nt], 0, 0, 0);
      }
    }
    __syncthreads();
  }

  // ---- phase 8: out = y + mlp + fc2_b (float4 stores) ----
  if (qq < 49) {
    float* dst = out + obase;
    #pragma unroll
    for (int nt = 0; nt < 6; ++nt) {
      float4 fb = *(const float4*)&fc2_b[16 * nt + 4 * gq];
      float4 v;
      v.x = y[nt][0] + accO[nt][0] + fb.x;
      v.y = y[nt][1] + accO[nt][1] + fb.y;
      v.z = y[nt][2] + accO[nt][2] + fb.z;
      v.w = y[nt][3] + accO[nt][3] + fb.w;
      *(float4*)&dst[16 * nt + 4 * gq] = v;
    }
  }
}

extern "C" void kernel_launch(void* const* d_in, const int* in_sizes, int n_in,
                              void* d_out, int out_size, void* d_ws, size_t ws_size,
                              hipStream_t stream) {
  const float* x         = (const float*)d_in[0];
  const float* attn_mask = (const float*)d_in[1];
  const int*   rel_index = (const int*)  d_in[2];
  const float* n1g       = (const float*)d_in[3];
  const float* n1b       = (const float*)d_in[4];
  const float* qkv_w     = (const float*)d_in[5];
  const float* qkv_b     = (const float*)d_in[6];
  const float* rel_tab   = (const float*)d_in[7];
  const float* proj_w    = (const float*)d_in[8];
  const float* proj_b    = (const float*)d_in[9];
  const float* n2g       = (const float*)d_in[10];
  const float* n2b       = (const float*)d_in[11];
  const float* fc1_w     = (const float*)d_in[12];
  const float* fc1_b     = (const float*)d_in[13];
  const float* fc2_w     = (const float*)d_in[14];
  const float* fc2_b     = (const float*)d_in[15];
  float* out = (float*)d_out;

  const int B = in_sizes[0] / (HW * HW * 96);
  const bool pre = ws_size >= (size_t)WTOT * 2;

  if (pre) {
    short* ws = (short*)d_ws;
    cvt_weights<<<(WTOT + 255) / 256, 256, 0, stream>>>(qkv_w, proj_w, fc1_w, fc2_w, ws);
    swin_mfma_kernel<true><<<B * 64, 256, 0, stream>>>(
        x, attn_mask, rel_index, n1g, n1b, qkv_w, qkv_b, rel_tab, proj_w, proj_b,
        n2g, n2b, fc1_w, fc1_b, fc2_w, fc2_b, (const short*)ws, out);
  } else {
    swin_mfma_kernel<false><<<B * 64, 256, 0, stream>>>(
        x, attn_mask, rel_index, n1g, n1b, qkv_w, qkv_b, rel_tab, proj_w, proj_b,
        n2g, n2b, fc1_w, fc1_b, fc2_w, fc2_b, (const short*)nullptr, out);
  }
}

// Round 12
// 170.081 us; speedup vs baseline: 1.1705x; 1.1705x over previous
//
#include <hip/hip_runtime.h>
#include <hip/hip_bf16.h>

// Swin block fully fused, bf16 MFMA. B=64, H=W=56, C=96, nh=3, d=32, WS=7, SS=3, N=49, nW=64.
// Round 12: round-10 attention (per-head, spill-free) + pipelined proj/MLP weight staging
// (ping-pong 9KB bufA/bufB in dead K/V region; issue -> compute -> barrier).
// Bias+mask via MFMA C-in; softmax without max-subtraction.
typedef __attribute__((ext_vector_type(8))) short short8;  // 8 bf16 = one A/B frag
typedef __attribute__((ext_vector_type(4))) float f32x4;   // C/D frag

constexpr int HW = 56;

// ---- LDS pool (bf16 elements). Frag-read bases 16B-aligned. ----
constexpr int SR    = 104;             // row stride for [64][96] token-major buffers
constexpr int SVT   = 200;             // row stride for vT [32][3*64]
constexpr int OFF_X = 0;               // [64][SR]: xln -> P (own row) -> fc1 h (own row)
constexpr int OFF_Q = 64 * SR;         // [64][SR]: q -> attn-out (own row) -> yn (own row)
constexpr int OFF_K = 2 * 64 * SR;     // [64][SR]: k ; after attention: bufA/bufB
constexpr int OFF_V = 3 * 64 * SR;     // [32][SVT]: v^T
constexpr int POOLN = OFF_V + 32 * SVT;  // 26368 shorts = 52736 B -> 3 blocks/CU
// dead region after attention: [OFF_K, POOLN) = 13056 shorts; bufA/bufB = 2*4608 = 9216 ✓

// ---- d_ws layout (bf16), frag-major: [set*512 + lane*8 + j] ----
constexpr int WQKV  = 0;               // 18 tiles (set = tile*3+s)
constexpr int WPROJ = 27648;           // 6 tiles: sets 0..17 (h0 = 0..8, h1 = 9..17)
constexpr int WFC1  = 36864;           // chunk-major: chunk cn = sets cn*18 .. cn*18+17
constexpr int WFC2  = 73728;           // chunk-major
constexpr int WTOT  = 110592;          // *2B = 221184 bytes

__device__ __forceinline__ ushort bfc(float f) {
  union { __hip_bfloat16 h; ushort u; } v;
  v.h = __float2bfloat16(f);
  return v.u;
}
__device__ __forceinline__ uint pk2(float a, float b) {
  union { __hip_bfloat162 h2; uint u; } v;
  v.h2 = __float22bfloat162_rn(make_float2(a, b));
  return v.u;
}
__device__ __forceinline__ void st4(short* p, float a, float b, float c, float d) {
  uint2 u; u.x = pk2(a, b); u.y = pk2(c, d);
  *(uint2*)p = u;
}
__device__ __forceinline__ short8 ldw8(const float* p) {
  float4 a = *(const float4*)p;
  float4 b = *(const float4*)(p + 4);
  short8 r;
  r[0] = (short)bfc(a.x); r[1] = (short)bfc(a.y); r[2] = (short)bfc(a.z); r[3] = (short)bfc(a.w);
  r[4] = (short)bfc(b.x); r[5] = (short)bfc(b.y); r[6] = (short)bfc(b.z); r[7] = (short)bfc(b.w);
  return r;
}
template<bool PRE>
__device__ __forceinline__ short8 wfrag(const short* wsb, int ts, int lane, const float* fsrc) {
  if constexpr (PRE) return *(const short8*)&wsb[(ts << 9) + lane * 8];
  else               return ldw8(fsrc);
}
// GELU sigmoid form: x * sigma(1.702 x)
__device__ __forceinline__ float gelu(float v) {
  return v / (1.0f + __expf(-1.702f * v));
}
// stage 9 sets (9216B) global->LDS, wave-split (wave w takes sets w, w+4, w+8)
__device__ __forceinline__ void stage9(const short* g0, short* l0, int wv, int lane) {
  #pragma unroll
  for (int s4 = 0; s4 < 3; ++s4) {
    int s = wv + 4 * s4;
    if (s < 9)
      __builtin_amdgcn_global_load_lds((const unsigned int*)(g0 + (s << 9) + lane * 8),
                                       (unsigned int*)(l0 + (s << 9)), 16, 0, 0);
  }
}

// one-shot weight conversion f32 -> bf16, frag-major (same layout as round 10)
__global__ __launch_bounds__(256) void cvt_weights(
    const float* __restrict__ qkv_w, const float* __restrict__ proj_w,
    const float* __restrict__ fc1_w, const float* __restrict__ fc2_w,
    short* __restrict__ ws)
{
  int idx = blockIdx.x * 256 + threadIdx.x;
  if (idx >= WTOT) return;
  int j = idx & 7, lane = (idx >> 3) & 63;
  int cl = lane & 15;
  int g  = 8 * (lane >> 4) + j;
  float v;
  if (idx < WPROJ) {
    int ts = idx >> 9; int tile = ts / 3, s = ts - 3 * tile;
    v = qkv_w[(size_t)(16 * tile + cl) * 96 + 32 * s + g];
  } else if (idx < WFC1) {
    int ts = (idx - WPROJ) >> 9; int tile = ts / 3, s = ts - 3 * tile;
    v = proj_w[(size_t)(16 * tile + cl) * 96 + 32 * s + g];
  } else if (idx < WFC2) {
    int ts = (idx - WFC1) >> 9; int T = ts / 3, s = ts - 3 * T;
    int cn = T / 6, nt = T - 6 * cn;
    v = fc1_w[(size_t)(96 * cn + 16 * nt + cl) * 96 + 32 * s + g];
  } else {
    int ts = (idx - WFC2) >> 9; int T = ts / 3, s = ts - 3 * T;
    int cn = T / 6, nt = T - 6 * cn;
    v = fc2_w[(size_t)(16 * nt + cl) * 384 + 96 * cn + 32 * s + g];
  }
  ws[idx] = (short)bfc(v);
}

template<bool PRE>
__global__ __launch_bounds__(256, 3) void swin_mfma_kernel(
    const float* __restrict__ x,          // [B,3136,96]
    const float* __restrict__ attn_mask,  // [64,49,49]
    const int*   __restrict__ rel_index,  // [2401]
    const float* __restrict__ n1g, const float* __restrict__ n1b,
    const float* __restrict__ qkv_w, const float* __restrict__ qkv_b,
    const float* __restrict__ rel_tab,    // [169,3]
    const float* __restrict__ proj_w, const float* __restrict__ proj_b,
    const float* __restrict__ n2g, const float* __restrict__ n2b,
    const float* __restrict__ fc1_w, const float* __restrict__ fc1_b,
    const float* __restrict__ fc2_w, const float* __restrict__ fc2_b,
    const short* __restrict__ wsw,
    float* __restrict__ out)              // [B,3136,96]
{
  __shared__ alignas(16) short pool[POOLN];
  short* bufA = (short*)&pool[OFF_K];
  short* bufB = (short*)&pool[OFF_K + 4608];

  const int tid  = threadIdx.x;
  const int wv   = tid >> 6;          // wave id = token 16-strip owner
  const int lane = tid & 63;
  const int ln   = lane & 15;
  const int gq   = lane >> 4;
  const int bw   = blockIdx.x;
  const int b    = bw >> 6, widx = bw & 63;
  const int wr   = widx >> 3, wc = widx & 7;

  const f32x4 zf = {0.f, 0.f, 0.f, 0.f};
  const int qq = 16 * wv + ln;        // this thread's token row

  auto gbase = [&](int n) -> size_t {
    int i = n / 7, j = n - 7 * i;
    int h = wr * 7 + i + 3; if (h >= HW) h -= HW;   // roll(-3)
    int w = wc * 7 + j + 3; if (w >= HW) w -= HW;
    return ((size_t)b * (HW * HW) + (size_t)h * HW + w) * 96;
  };
  const size_t obase = gbase(qq < 49 ? qq : 48);

  // ---- stage 1: token-per-thread-column load + LN1 -> xln; raw x kept in VGPRs ----
  float xraw[6][4];
  {
    if (qq < 49) {
      const float* xr = x + obase;
      #pragma unroll
      for (int nt = 0; nt < 6; ++nt) {
        float4 v = *(const float4*)&xr[16 * nt + 4 * gq];
        xraw[nt][0] = v.x; xraw[nt][1] = v.y; xraw[nt][2] = v.z; xraw[nt][3] = v.w;
      }
    } else {
      #pragma unroll
      for (int nt = 0; nt < 6; ++nt)
        xraw[nt][0] = xraw[nt][1] = xraw[nt][2] = xraw[nt][3] = 0.f;
    }
    float s1 = 0.f, s2 = 0.f;
    #pragma unroll
    for (int nt = 0; nt < 6; ++nt)
      #pragma unroll
      for (int r = 0; r < 4; ++r) { s1 += xraw[nt][r]; s2 += xraw[nt][r] * xraw[nt][r]; }
    s1 += __shfl_xor(s1, 16, 64); s1 += __shfl_xor(s1, 32, 64);
    s2 += __shfl_xor(s2, 16, 64); s2 += __shfl_xor(s2, 32, 64);
    float mean = s1 * (1.f / 96.f);
    float inv  = rsqrtf(s2 * (1.f / 96.f) - mean * mean + 1e-5f);
    #pragma unroll
    for (int nt = 0; nt < 6; ++nt) {
      float4 g4 = *(const float4*)&n1g[16 * nt + 4 * gq];
      float4 b4 = *(const float4*)&n1b[16 * nt + 4 * gq];
      st4(&pool[OFF_X + qq * SR + 16 * nt + 4 * gq],
          (xraw[nt][0] - mean) * inv * g4.x + b4.x,
          (xraw[nt][1] - mean) * inv * g4.y + b4.y,
          (xraw[nt][2] - mean) * inv * g4.z + b4.z,
          (xraw[nt][3] - mean) * inv * g4.w + b4.w);
    }
  }
  __syncthreads();

  // ---- stage 2: QKV. Q/K channel-rows; V transposed token-rows. N-split across waves ----
  {
    short8 af[3][4];
    #pragma unroll
    for (int s = 0; s < 3; ++s)
      #pragma unroll
      for (int m = 0; m < 4; ++m)
        af[s][m] = *(const short8*)&pool[OFF_X + (16 * m + ln) * SR + 32 * s + 8 * gq];

    for (int t = wv; t < 18; t += 4) {
      short8 wf[3];
      #pragma unroll
      for (int s = 0; s < 3; ++s)
        wf[s] = wfrag<PRE>(wsw + WQKV, t * 3 + s, lane,
                           qkv_w + (size_t)(16 * t + ln) * 96 + 32 * s + 8 * gq);
      int which = t / 6;               // 0=q 1=k 2=v
      if (which == 2) {
        int d  = 16 * (t - 12) + ln;
        float bv = qkv_b[192 + d];
        int dd = d & 31, hh = d >> 5;
        #pragma unroll
        for (int m = 0; m < 4; ++m) {
          f32x4 acc = zf;
          #pragma unroll
          for (int s = 0; s < 3; ++s)
            acc = __builtin_amdgcn_mfma_f32_16x16x32_bf16(af[s][m], wf[s], acc, 0, 0, 0);
          st4(&pool[OFF_V + dd * SVT + hh * 64 + 16 * m + 4 * gq],
              acc[0] + bv, acc[1] + bv, acc[2] + bv, acc[3] + bv);
        }
      } else {
        float4 b4 = *(const float4*)&qkv_b[16 * t + 4 * gq];
        #pragma unroll
        for (int m = 0; m < 4; ++m) {
          f32x4 acc = zf;
          #pragma unroll
          for (int s = 0; s < 3; ++s)
            acc = __builtin_amdgcn_mfma_f32_16x16x32_bf16(wf[s], af[s][m], acc, 0, 0, 0);
          int tok = 16 * m + ln;
          float v0 = acc[0] + b4.x, v1 = acc[1] + b4.y, v2 = acc[2] + b4.z, v3 = acc[3] + b4.w;
          if (which == 0) {
            const float sc_ = 0.17677669529663687f;
            st4(&pool[OFF_Q + tok * SR + 16 * t + 4 * gq], v0 * sc_, v1 * sc_, v2 * sc_, v3 * sc_);
          } else {
            st4(&pool[OFF_K + tok * SR + 16 * (t - 6) + 4 * gq], v0, v1, v2, v3);
          }
        }
      }
    }
  }
  __syncthreads();

  // ---- stage 3: attention, per-head (bias+mask via C-in, no-max-sub softmax) ----
  int   relvv[4][4];
  float maskb[4][4];
  {
    int qc = qq < 49 ? qq : 48;
    #pragma unroll
    for (int nt = 0; nt < 4; ++nt)
      #pragma unroll
      for (int r = 0; r < 4; ++r) {
        int key = 16 * nt + 4 * gq + r;
        if (key < 49) {
          int qk = qc * 49 + key;
          relvv[nt][r] = rel_index[qk];
          maskb[nt][r] = attn_mask[(size_t)widx * 2401 + qk];
        } else {
          relvv[nt][r] = 0;
          maskb[nt][r] = -1e30f;   // swamps rel bias; exp -> 0
        }
      }
  }

  for (int h = 0; h < 3; ++h) {
    short8 bq = *(const short8*)&pool[OFF_Q + qq * SR + h * 32 + 8 * gq];
    f32x4 sc[4];
    #pragma unroll
    for (int nt = 0; nt < 4; ++nt) {
      f32x4 bia;
      #pragma unroll
      for (int r = 0; r < 4; ++r)
        bia[r] = rel_tab[relvv[nt][r] * 3 + h] + maskb[nt][r];
      short8 ak = *(const short8*)&pool[OFF_K + (16 * nt + ln) * SR + h * 32 + 8 * gq];
      sc[nt] = __builtin_amdgcn_mfma_f32_16x16x32_bf16(ak, bq, bia, 0, 0, 0);
    }
    float pv[4][4];
    float sum = 0.f;
    #pragma unroll
    for (int nt = 0; nt < 4; ++nt)
      #pragma unroll
      for (int r = 0; r < 4; ++r) { pv[nt][r] = __expf(sc[nt][r]); sum += pv[nt][r]; }
    sum += __shfl_xor(sum, 16, 64);
    sum += __shfl_xor(sum, 32, 64);
    float inv = 1.f / sum;
    #pragma unroll
    for (int nt = 0; nt < 4; ++nt)
      st4(&pool[OFF_X + qq * SR + 16 * nt + 4 * gq],
          pv[nt][0] * inv, pv[nt][1] * inv, pv[nt][2] * inv, pv[nt][3] * inv);

    short8 bp0 = *(const short8*)&pool[OFF_X + qq * SR + 8 * gq];
    short8 bp1 = *(const short8*)&pool[OFF_X + qq * SR + 32 + 8 * gq];
    #pragma unroll
    for (int dt = 0; dt < 2; ++dt) {
      short8 av0 = *(const short8*)&pool[OFF_V + (16 * dt + ln) * SVT + h * 64 + 8 * gq];
      short8 av1 = *(const short8*)&pool[OFF_V + (16 * dt + ln) * SVT + h * 64 + 32 + 8 * gq];
      f32x4 o = __builtin_amdgcn_mfma_f32_16x16x32_bf16(av0, bp0, zf, 0, 0, 0);
      o = __builtin_amdgcn_mfma_f32_16x16x32_bf16(av1, bp1, o, 0, 0, 0);
      st4(&pool[OFF_Q + qq * SR + h * 32 + 16 * dt + 4 * gq], o[0], o[1], o[2], o[3]);
    }
  }

  // ---- stage 4: pipelined proj + LN2 ----
  short8 ao[3];
  #pragma unroll
  for (int s = 0; s < 3; ++s)
    ao[s] = *(const short8*)&pool[OFF_Q + qq * SR + 32 * s + 8 * gq];
  __syncthreads();   // all waves done with K/V reads -> bufA/bufB usable

  if constexpr (PRE) stage9(wsw + WPROJ, bufA, wv, lane);   // the single exposed stage
  __syncthreads();

  if constexpr (PRE) stage9(wsw + WPROJ + 9 * 512, bufB, wv, lane);
  float y[6][4];
  #pragma unroll
  for (int nt = 0; nt < 3; ++nt) {
    f32x4 acc = zf;
    #pragma unroll
    for (int s = 0; s < 3; ++s) {
      short8 wfr = PRE ? *(const short8*)&bufA[(nt * 3 + s) * 512 + lane * 8]
                       : ldw8(proj_w + (size_t)(16 * nt + ln) * 96 + 32 * s + 8 * gq);
      acc = __builtin_amdgcn_mfma_f32_16x16x32_bf16(wfr, ao[s], acc, 0, 0, 0);
    }
    float4 pb = *(const float4*)&proj_b[16 * nt + 4 * gq];
    y[nt][0] = acc[0] + pb.x + xraw[nt][0];
    y[nt][1] = acc[1] + pb.y + xraw[nt][1];
    y[nt][2] = acc[2] + pb.z + xraw[nt][2];
    y[nt][3] = acc[3] + pb.w + xraw[nt][3];
  }
  __syncthreads();   // bufB landed; bufA reads done

  if constexpr (PRE) stage9(wsw + WFC1, bufA, wv, lane);
  #pragma unroll
  for (int nt = 3; nt < 6; ++nt) {
    f32x4 acc = zf;
    #pragma unroll
    for (int s = 0; s < 3; ++s) {
      short8 wfr = PRE ? *(const short8*)&bufB[((nt - 3) * 3 + s) * 512 + lane * 8]
                       : ldw8(proj_w + (size_t)(16 * nt + ln) * 96 + 32 * s + 8 * gq);
      acc = __builtin_amdgcn_mfma_f32_16x16x32_bf16(wfr, ao[s], acc, 0, 0, 0);
    }
    float4 pb = *(const float4*)&proj_b[16 * nt + 4 * gq];
    y[nt][0] = acc[0] + pb.x + xraw[nt][0];
    y[nt][1] = acc[1] + pb.y + xraw[nt][1];
    y[nt][2] = acc[2] + pb.z + xraw[nt][2];
    y[nt][3] = acc[3] + pb.w + xraw[nt][3];
  }
  {
    float s1 = 0.f, s2 = 0.f;
    #pragma unroll
    for (int nt = 0; nt < 6; ++nt)
      #pragma unroll
      for (int r = 0; r < 4; ++r) { s1 += y[nt][r]; s2 += y[nt][r] * y[nt][r]; }
    s1 += __shfl_xor(s1, 16, 64); s1 += __shfl_xor(s1, 32, 64);
    s2 += __shfl_xor(s2, 16, 64); s2 += __shfl_xor(s2, 32, 64);
    float mean = s1 * (1.f / 96.f);
    float inv  = rsqrtf(s2 * (1.f / 96.f) - mean * mean + 1e-5f);
    #pragma unroll
    for (int nt = 0; nt < 6; ++nt) {
      float4 g4 = *(const float4*)&n2g[16 * nt + 4 * gq];
      float4 b4 = *(const float4*)&n2b[16 * nt + 4 * gq];
      st4(&pool[OFF_Q + qq * SR + 16 * nt + 4 * gq],
          (y[nt][0] - mean) * inv * g4.x + b4.x,
          (y[nt][1] - mean) * inv * g4.y + b4.y,
          (y[nt][2] - mean) * inv * g4.z + b4.z,
          (y[nt][3] - mean) * inv * g4.w + b4.w);
    }
  }
  short8 ay[3];
  #pragma unroll
  for (int s = 0; s < 3; ++s)
    ay[s] = *(const short8*)&pool[OFF_Q + qq * SR + 32 * s + 8 * gq];
  __syncthreads();   // bufA (fc1.c0.h0) landed; bufB reads done

  // ---- stage 5: MLP, 4 chunks x 4 pipelined half-stages ----
  f32x4 accO[6] = {zf, zf, zf, zf, zf, zf};
  for (int cn = 0; cn < 4; ++cn) {
    // (a) stage fc1.cn.h1 -> bufB || fc1 nt 0..2 from bufA
    if constexpr (PRE) stage9(wsw + WFC1 + (cn * 18 + 9) * 512, bufB, wv, lane);
    #pragma unroll
    for (int nt = 0; nt < 3; ++nt) {
      f32x4 acc = zf;
      #pragma unroll
      for (int s = 0; s < 3; ++s) {
        short8 wfr = PRE ? *(const short8*)&bufA[(nt * 3 + s) * 512 + lane * 8]
                         : ldw8(fc1_w + (size_t)(96 * cn + 16 * nt + ln) * 96 + 32 * s + 8 * gq);
        acc = __builtin_amdgcn_mfma_f32_16x16x32_bf16(wfr, ay[s], acc, 0, 0, 0);
      }
      float4 b1 = *(const float4*)&fc1_b[96 * cn + 16 * nt + 4 * gq];
      st4(&pool[OFF_X + qq * SR + 16 * nt + 4 * gq],
          gelu(acc[0] + b1.x), gelu(acc[1] + b1.y),
          gelu(acc[2] + b1.z), gelu(acc[3] + b1.w));
    }
    __syncthreads();
    // (b) stage fc2.cn.h0 -> bufA || fc1 nt 3..5 from bufB; then ah frags (own row)
    if constexpr (PRE) stage9(wsw + WFC2 + (cn * 18) * 512, bufA, wv, lane);
    #pragma unroll
    for (int nt = 3; nt < 6; ++nt) {
      f32x4 acc = zf;
      #pragma unroll
      for (int s = 0; s < 3; ++s) {
        short8 wfr = PRE ? *(const short8*)&bufB[((nt - 3) * 3 + s) * 512 + lane * 8]
                         : ldw8(fc1_w + (size_t)(96 * cn + 16 * nt + ln) * 96 + 32 * s + 8 * gq);
        acc = __builtin_amdgcn_mfma_f32_16x16x32_bf16(wfr, ay[s], acc, 0, 0, 0);
      }
      float4 b1 = *(const float4*)&fc1_b[96 * cn + 16 * nt + 4 * gq];
      st4(&pool[OFF_X + qq * SR + 16 * nt + 4 * gq],
          gelu(acc[0] + b1.x), gelu(acc[1] + b1.y),
          gelu(acc[2] + b1.z), gelu(acc[3] + b1.w));
    }
    short8 ah[3];
    #pragma unroll
    for (int s = 0; s < 3; ++s)
      ah[s] = *(const short8*)&pool[OFF_X + qq * SR + 32 * s + 8 * gq];
    __syncthreads();
    // (c) stage fc2.cn.h1 -> bufB || fc2 nt 0..2 from bufA
    if constexpr (PRE) stage9(wsw + WFC2 + (cn * 18 + 9) * 512, bufB, wv, lane);
    #pragma unroll
    for (int nt = 0; nt < 3; ++nt) {
      #pragma unroll
      for (int s = 0; s < 3; ++s) {
        short8 wfr = PRE ? *(const short8*)&bufA[(nt * 3 + s) * 512 + lane * 8]
                         : ldw8(fc2_w + (size_t)(16 * nt + ln) * 384 + 96 * cn + 32 * s + 8 * gq);
        accO[nt] = __builtin_amdgcn_mfma_f32_16x16x32_bf16(wfr, ah[s], accO[nt], 0, 0, 0);
      }
    }
    __syncthreads();
    // (d) stage fc1.(cn+1).h0 -> bufA || fc2 nt 3..5 from bufB
    if constexpr (PRE) { if (cn < 3) stage9(wsw + WFC1 + ((cn + 1) * 18) * 512, bufA, wv, lane); }
    #pragma unroll
    for (int nt = 3; nt < 6; ++nt) {
      #pragma unroll
      for (int s = 0; s < 3; ++s) {
        short8 wfr = PRE ? *(const short8*)&bufB[((nt - 3) * 3 + s) * 512 + lane * 8]
                         : ldw8(fc2_w + (size_t)(16 * nt + ln) * 384 + 96 * cn + 32 * s + 8 * gq);
        accO[nt] = __builtin_amdgcn_mfma_f32_16x16x32_bf16(wfr, ah[s], accO[nt], 0, 0, 0);
      }
    }
    __syncthreads();
  }

  // ---- stage 6: out = y + mlp + fc2_b (float4 stores) ----
  if (qq < 49) {
    float* dst = out + obase;
    #pragma unroll
    for (int nt = 0; nt < 6; ++nt) {
      float4 fb = *(const float4*)&fc2_b[16 * nt + 4 * gq];
      float4 v;
      v.x = y[nt][0] + accO[nt][0] + fb.x;
      v.y = y[nt][1] + accO[nt][1] + fb.y;
      v.z = y[nt][2] + accO[nt][2] + fb.z;
      v.w = y[nt][3] + accO[nt][3] + fb.w;
      *(float4*)&dst[16 * nt + 4 * gq] = v;
    }
  }
}

extern "C" void kernel_launch(void* const* d_in, const int* in_sizes, int n_in,
                              void* d_out, int out_size, void* d_ws, size_t ws_size,
                              hipStream_t stream) {
  const float* x         = (const float*)d_in[0];
  const float* attn_mask = (const float*)d_in[1];
  const int*   rel_index = (const int*)  d_in[2];
  const float* n1g       = (const float*)d_in[3];
  const float* n1b       = (const float*)d_in[4];
  const float* qkv_w     = (const float*)d_in[5];
  const float* qkv_b     = (const float*)d_in[6];
  const float* rel_tab   = (const float*)d_in[7];
  const float* proj_w    = (const float*)d_in[8];
  const float* proj_b    = (const float*)d_in[9];
  const float* n2g       = (const float*)d_in[10];
  const float* n2b       = (const float*)d_in[11];
  const float* fc1_w     = (const float*)d_in[12];
  const float* fc1_b     = (const float*)d_in[13];
  const float* fc2_w     = (const float*)d_in[14];
  const float* fc2_b     = (const float*)d_in[15];
  float* out = (float*)d_out;

  const int B = in_sizes[0] / (HW * HW * 96);
  const bool pre = ws_size >= (size_t)WTOT * 2;

  if (pre) {
    short* ws = (short*)d_ws;
    cvt_weights<<<(WTOT + 255) / 256, 256, 0, stream>>>(qkv_w, proj_w, fc1_w, fc2_w, ws);
    swin_mfma_kernel<true><<<B * 64, 256, 0, stream>>>(
        x, attn_mask, rel_index, n1g, n1b, qkv_w, qkv_b, rel_tab, proj_w, proj_b,
        n2g, n2b, fc1_w, fc1_b, fc2_w, fc2_b, (const short*)ws, out);
  } else {
    swin_mfma_kernel<false><<<B * 64, 256, 0, stream>>>(
        x, attn_mask, rel_index, n1g, n1b, qkv_w, qkv_b, rel_tab, proj_w, proj_b,
        n2g, n2b, fc1_w, fc1_b, fc2_w, fc2_b, (const short*)nullptr, out);
  }
}

// Round 13
// 155.935 us; speedup vs baseline: 1.2767x; 1.0907x over previous
//
#include <hip/hip_runtime.h>
#include <hip/hip_bf16.h>

// Swin block fully fused, bf16 MFMA. B=64, H=W=56, C=96, nh=3, d=32, WS=7, SS=3, N=49, nW=64.
// Round 13: round-12 structure + precomputed fused bias planes (rel+mask -> f32x4 C-in),
// rcpf in gelu/softmax, Q-scale folded into preconverted weights, setprio around MFMA.
typedef __attribute__((ext_vector_type(8))) short short8;  // 8 bf16 = one A/B frag
typedef __attribute__((ext_vector_type(4))) float f32x4;   // C/D frag

constexpr int HW = 56;

// ---- LDS pool (bf16 elements). Frag-read bases 16B-aligned. ----
constexpr int SR    = 104;             // row stride for [64][96] token-major buffers
constexpr int SVT   = 200;             // row stride for vT [32][3*64]
constexpr int OFF_X = 0;               // [64][SR]: xln -> P (own row) -> fc1 h (own row)
constexpr int OFF_Q = 64 * SR;         // [64][SR]: q -> attn-out (own row) -> yn (own row)
constexpr int OFF_K = 2 * 64 * SR;     // [64][SR]: k ; after attention: bufA/bufB
constexpr int OFF_V = 3 * 64 * SR;     // [32][SVT]: v^T
constexpr int POOLN = OFF_V + 32 * SVT;  // 26368 shorts = 52736 B -> 3 blocks/CU

// ---- d_ws layout: bf16 weights frag-major [set*512 + lane*8 + j], then f32 bias planes ----
constexpr int WQKV  = 0;               // 18 tiles (set = tile*3+s); Q tiles pre-scaled by d^-0.5
constexpr int WPROJ = 27648;           // 6 tiles: sets 0..17
constexpr int WFC1  = 36864;           // chunk-major: chunk cn = sets cn*18 .. cn*18+17
constexpr int WFC2  = 73728;           // chunk-major
constexpr int WTOT  = 110592;          // *2B = 221184 bytes
constexpr int BIASN = 64 * 3 * 49 * 64;           // f32 elements
constexpr size_t WS_M1 = (size_t)WTOT * 2;        // weights only
constexpr size_t WS_M2 = WS_M1 + (size_t)BIASN * 4;  // + bias planes

__device__ __forceinline__ ushort bfc(float f) {
  union { __hip_bfloat16 h; ushort u; } v;
  v.h = __float2bfloat16(f);
  return v.u;
}
__device__ __forceinline__ uint pk2(float a, float b) {
  union { __hip_bfloat162 h2; uint u; } v;
  v.h2 = __float22bfloat162_rn(make_float2(a, b));
  return v.u;
}
__device__ __forceinline__ void st4(short* p, float a, float b, float c, float d) {
  uint2 u; u.x = pk2(a, b); u.y = pk2(c, d);
  *(uint2*)p = u;
}
__device__ __forceinline__ short8 ldw8(const float* p) {
  float4 a = *(const float4*)p;
  float4 b = *(const float4*)(p + 4);
  short8 r;
  r[0] = (short)bfc(a.x); r[1] = (short)bfc(a.y); r[2] = (short)bfc(a.z); r[3] = (short)bfc(a.w);
  r[4] = (short)bfc(b.x); r[5] = (short)bfc(b.y); r[6] = (short)bfc(b.z); r[7] = (short)bfc(b.w);
  return r;
}
template<bool PRE>
__device__ __forceinline__ short8 wfrag(const short* wsb, int ts, int lane, const float* fsrc) {
  if constexpr (PRE) return *(const short8*)&wsb[(ts << 9) + lane * 8];
  else               return ldw8(fsrc);
}
// GELU sigmoid form with fast rcp: x * sigma(1.702 x)
__device__ __forceinline__ float gelu(float v) {
  return v * __builtin_amdgcn_rcpf(1.0f + __expf(-1.702f * v));
}
// stage 9 sets (9216B) global->LDS, wave-split (wave w takes sets w, w+4, w+8)
__device__ __forceinline__ void stage9(const short* g0, short* l0, int wv, int lane) {
  #pragma unroll
  for (int s4 = 0; s4 < 3; ++s4) {
    int s = wv + 4 * s4;
    if (s < 9)
      __builtin_amdgcn_global_load_lds((const unsigned int*)(g0 + (s << 9) + lane * 8),
                                       (unsigned int*)(l0 + (s << 9)), 16, 0, 0);
  }
}

// one-shot weight conversion f32 -> bf16, frag-major; Q tiles pre-scaled by d^-0.5
__global__ __launch_bounds__(256) void cvt_weights(
    const float* __restrict__ qkv_w, const float* __restrict__ proj_w,
    const float* __restrict__ fc1_w, const float* __restrict__ fc2_w,
    short* __restrict__ ws)
{
  int idx = blockIdx.x * 256 + threadIdx.x;
  if (idx >= WTOT) return;
  int j = idx & 7, lane = (idx >> 3) & 63;
  int cl = lane & 15;
  int g  = 8 * (lane >> 4) + j;
  float v;
  if (idx < WPROJ) {
    int ts = idx >> 9; int tile = ts / 3, s = ts - 3 * tile;
    v = qkv_w[(size_t)(16 * tile + cl) * 96 + 32 * s + g];
    if (tile < 6) v *= 0.17677669529663687f;   // fold Q scale
  } else if (idx < WFC1) {
    int ts = (idx - WPROJ) >> 9; int tile = ts / 3, s = ts - 3 * tile;
    v = proj_w[(size_t)(16 * tile + cl) * 96 + 32 * s + g];
  } else if (idx < WFC2) {
    int ts = (idx - WFC1) >> 9; int T = ts / 3, s = ts - 3 * T;
    int cn = T / 6, nt = T - 6 * cn;
    v = fc1_w[(size_t)(96 * cn + 16 * nt + cl) * 96 + 32 * s + g];
  } else {
    int ts = (idx - WFC2) >> 9; int T = ts / 3, s = ts - 3 * T;
    int cn = T / 6, nt = T - 6 * cn;
    v = fc2_w[(size_t)(16 * nt + cl) * 384 + 96 * cn + 32 * s + g];
  }
  ws[idx] = (short)bfc(v);
}

// one-shot fused bias planes: bias3[widx][h][q][64] = rel_bias + mask (k>=49 -> -1e30)
__global__ __launch_bounds__(256) void prep_bias(
    const float* __restrict__ attn_mask, const int* __restrict__ rel_index,
    const float* __restrict__ rel_tab, float* __restrict__ bias3)
{
  int idx = blockIdx.x * 256 + threadIdx.x;
  if (idx >= BIASN) return;
  int k = idx & 63;
  int t = idx >> 6;             // (widx*3 + h)*49 + q
  int q = t % 49;
  int wh = t / 49;              // widx*3 + h
  int h = wh % 3, w = wh / 3;
  float v = -1e30f;
  if (k < 49) {
    int qk = q * 49 + k;
    v = rel_tab[rel_index[qk] * 3 + h] + attn_mask[(size_t)w * 2401 + qk];
  }
  bias3[idx] = v;
}

template<int MODE>   // 0: no ws; 1: +bf16 weights; 2: +bias planes
__global__ __launch_bounds__(256, 3) void swin_mfma_kernel(
    const float* __restrict__ x,          // [B,3136,96]
    const float* __restrict__ attn_mask,  // [64,49,49]
    const int*   __restrict__ rel_index,  // [2401]
    const float* __restrict__ n1g, const float* __restrict__ n1b,
    const float* __restrict__ qkv_w, const float* __restrict__ qkv_b,
    const float* __restrict__ rel_tab,    // [169,3]
    const float* __restrict__ proj_w, const float* __restrict__ proj_b,
    const float* __restrict__ n2g, const float* __restrict__ n2b,
    const float* __restrict__ fc1_w, const float* __restrict__ fc1_b,
    const float* __restrict__ fc2_w, const float* __restrict__ fc2_b,
    const short* __restrict__ wsw,
    const float* __restrict__ bias3,
    float* __restrict__ out)              // [B,3136,96]
{
  constexpr bool PRE = (MODE >= 1);
  __shared__ alignas(16) short pool[POOLN];
  short* bufA = (short*)&pool[OFF_K];
  short* bufB = (short*)&pool[OFF_K + 4608];

  const int tid  = threadIdx.x;
  const int wv   = tid >> 6;          // wave id = token 16-strip owner
  const int lane = tid & 63;
  const int ln   = lane & 15;
  const int gq   = lane >> 4;
  const int bw   = blockIdx.x;
  const int b    = bw >> 6, widx = bw & 63;
  const int wr   = widx >> 3, wc = widx & 7;

  const f32x4 zf = {0.f, 0.f, 0.f, 0.f};
  const int qq = 16 * wv + ln;        // this thread's token row

  auto gbase = [&](int n) -> size_t {
    int i = n / 7, j = n - 7 * i;
    int h = wr * 7 + i + 3; if (h >= HW) h -= HW;   // roll(-3)
    int w = wc * 7 + j + 3; if (w >= HW) w -= HW;
    return ((size_t)b * (HW * HW) + (size_t)h * HW + w) * 96;
  };
  const size_t obase = gbase(qq < 49 ? qq : 48);

  // ---- stage 1: token-per-thread-column load + LN1 -> xln; raw x kept in VGPRs ----
  float xraw[6][4];
  {
    if (qq < 49) {
      const float* xr = x + obase;
      #pragma unroll
      for (int nt = 0; nt < 6; ++nt) {
        float4 v = *(const float4*)&xr[16 * nt + 4 * gq];
        xraw[nt][0] = v.x; xraw[nt][1] = v.y; xraw[nt][2] = v.z; xraw[nt][3] = v.w;
      }
    } else {
      #pragma unroll
      for (int nt = 0; nt < 6; ++nt)
        xraw[nt][0] = xraw[nt][1] = xraw[nt][2] = xraw[nt][3] = 0.f;
    }
    float s1 = 0.f, s2 = 0.f;
    #pragma unroll
    for (int nt = 0; nt < 6; ++nt)
      #pragma unroll
      for (int r = 0; r < 4; ++r) { s1 += xraw[nt][r]; s2 += xraw[nt][r] * xraw[nt][r]; }
    s1 += __shfl_xor(s1, 16, 64); s1 += __shfl_xor(s1, 32, 64);
    s2 += __shfl_xor(s2, 16, 64); s2 += __shfl_xor(s2, 32, 64);
    float mean = s1 * (1.f / 96.f);
    float inv  = rsqrtf(s2 * (1.f / 96.f) - mean * mean + 1e-5f);
    #pragma unroll
    for (int nt = 0; nt < 6; ++nt) {
      float4 g4 = *(const float4*)&n1g[16 * nt + 4 * gq];
      float4 b4 = *(const float4*)&n1b[16 * nt + 4 * gq];
      st4(&pool[OFF_X + qq * SR + 16 * nt + 4 * gq],
          (xraw[nt][0] - mean) * inv * g4.x + b4.x,
          (xraw[nt][1] - mean) * inv * g4.y + b4.y,
          (xraw[nt][2] - mean) * inv * g4.z + b4.z,
          (xraw[nt][3] - mean) * inv * g4.w + b4.w);
    }
  }
  __syncthreads();

  // ---- stage 2: QKV. Q/K channel-rows; V transposed token-rows. N-split across waves ----
  {
    short8 af[3][4];
    #pragma unroll
    for (int s = 0; s < 3; ++s)
      #pragma unroll
      for (int m = 0; m < 4; ++m)
        af[s][m] = *(const short8*)&pool[OFF_X + (16 * m + ln) * SR + 32 * s + 8 * gq];

    const float sc_ = 0.17677669529663687f;
    for (int t = wv; t < 18; t += 4) {
      short8 wf[3];
      #pragma unroll
      for (int s = 0; s < 3; ++s)
        wf[s] = wfrag<PRE>(wsw + WQKV, t * 3 + s, lane,
                           qkv_w + (size_t)(16 * t + ln) * 96 + 32 * s + 8 * gq);
      int which = t / 6;               // 0=q 1=k 2=v
      if (which == 2) {
        int d  = 16 * (t - 12) + ln;
        float bv = qkv_b[192 + d];
        int dd = d & 31, hh = d >> 5;
        __builtin_amdgcn_s_setprio(1);
        #pragma unroll
        for (int m = 0; m < 4; ++m) {
          f32x4 acc = zf;
          #pragma unroll
          for (int s = 0; s < 3; ++s)
            acc = __builtin_amdgcn_mfma_f32_16x16x32_bf16(af[s][m], wf[s], acc, 0, 0, 0);
          st4(&pool[OFF_V + dd * SVT + hh * 64 + 16 * m + 4 * gq],
              acc[0] + bv, acc[1] + bv, acc[2] + bv, acc[3] + bv);
        }
        __builtin_amdgcn_s_setprio(0);
      } else {
        float4 b4 = *(const float4*)&qkv_b[16 * t + 4 * gq];
        if (which == 0) {
          if constexpr (PRE) { b4.x *= sc_; b4.y *= sc_; b4.z *= sc_; b4.w *= sc_; }
        }
        __builtin_amdgcn_s_setprio(1);
        #pragma unroll
        for (int m = 0; m < 4; ++m) {
          f32x4 acc = zf;
          #pragma unroll
          for (int s = 0; s < 3; ++s)
            acc = __builtin_amdgcn_mfma_f32_16x16x32_bf16(wf[s], af[s][m], acc, 0, 0, 0);
          int tok = 16 * m + ln;
          float v0 = acc[0] + b4.x, v1 = acc[1] + b4.y, v2 = acc[2] + b4.z, v3 = acc[3] + b4.w;
          if (which == 0) {
            if constexpr (PRE)
              st4(&pool[OFF_Q + tok * SR + 16 * t + 4 * gq], v0, v1, v2, v3);
            else
              st4(&pool[OFF_Q + tok * SR + 16 * t + 4 * gq], v0 * sc_, v1 * sc_, v2 * sc_, v3 * sc_);
          } else {
            st4(&pool[OFF_K + tok * SR + 16 * (t - 6) + 4 * gq], v0, v1, v2, v3);
          }
        }
        __builtin_amdgcn_s_setprio(0);
      }
    }
  }
  __syncthreads();

  // ---- stage 3: attention, per-head (bias+mask via C-in, no-max-sub softmax, rcp) ----
  const int qc = qq < 49 ? qq : 48;
  int   relvv[4][4];
  float maskb[4][4];
  if constexpr (MODE < 2) {
    #pragma unroll
    for (int nt = 0; nt < 4; ++nt)
      #pragma unroll
      for (int r = 0; r < 4; ++r) {
        int key = 16 * nt + 4 * gq + r;
        if (key < 49) {
          int qk = qc * 49 + key;
          relvv[nt][r] = rel_index[qk];
          maskb[nt][r] = attn_mask[(size_t)widx * 2401 + qk];
        } else {
          relvv[nt][r] = 0;
          maskb[nt][r] = -1e30f;
        }
      }
  }
  const float* bph = nullptr;
  if constexpr (MODE == 2) bph = bias3 + ((size_t)widx * 3 * 49 + qc) * 64;

  for (int h = 0; h < 3; ++h) {
    short8 bq = *(const short8*)&pool[OFF_Q + qq * SR + h * 32 + 8 * gq];
    f32x4 sc[4];
    __builtin_amdgcn_s_setprio(1);
    #pragma unroll
    for (int nt = 0; nt < 4; ++nt) {
      f32x4 bia;
      if constexpr (MODE == 2) {
        bia = *(const f32x4*)&bph[h * 3136 + 16 * nt + 4 * gq];
      } else {
        #pragma unroll
        for (int r = 0; r < 4; ++r)
          bia[r] = rel_tab[relvv[nt][r] * 3 + h] + maskb[nt][r];
      }
      short8 ak = *(const short8*)&pool[OFF_K + (16 * nt + ln) * SR + h * 32 + 8 * gq];
      sc[nt] = __builtin_amdgcn_mfma_f32_16x16x32_bf16(ak, bq, bia, 0, 0, 0);
    }
    __builtin_amdgcn_s_setprio(0);
    float pv[4][4];
    float sum = 0.f;
    #pragma unroll
    for (int nt = 0; nt < 4; ++nt)
      #pragma unroll
      for (int r = 0; r < 4; ++r) { pv[nt][r] = __expf(sc[nt][r]); sum += pv[nt][r]; }
    sum += __shfl_xor(sum, 16, 64);
    sum += __shfl_xor(sum, 32, 64);
    float inv = __builtin_amdgcn_rcpf(sum);
    #pragma unroll
    for (int nt = 0; nt < 4; ++nt)
      st4(&pool[OFF_X + qq * SR + 16 * nt + 4 * gq],
          pv[nt][0] * inv, pv[nt][1] * inv, pv[nt][2] * inv, pv[nt][3] * inv);

    short8 bp0 = *(const short8*)&pool[OFF_X + qq * SR + 8 * gq];
    short8 bp1 = *(const short8*)&pool[OFF_X + qq * SR + 32 + 8 * gq];
    __builtin_amdgcn_s_setprio(1);
    #pragma unroll
    for (int dt = 0; dt < 2; ++dt) {
      short8 av0 = *(const short8*)&pool[OFF_V + (16 * dt + ln) * SVT + h * 64 + 8 * gq];
      short8 av1 = *(const short8*)&pool[OFF_V + (16 * dt + ln) * SVT + h * 64 + 32 + 8 * gq];
      f32x4 o = __builtin_amdgcn_mfma_f32_16x16x32_bf16(av0, bp0, zf, 0, 0, 0);
      o = __builtin_amdgcn_mfma_f32_16x16x32_bf16(av1, bp1, o, 0, 0, 0);
      st4(&pool[OFF_Q + qq * SR + h * 32 + 16 * dt + 4 * gq], o[0], o[1], o[2], o[3]);
    }
    __builtin_amdgcn_s_setprio(0);
  }

  // ---- stage 4: pipelined proj + LN2 ----
  short8 ao[3];
  #pragma unroll
  for (int s = 0; s < 3; ++s)
    ao[s] = *(const short8*)&pool[OFF_Q + qq * SR + 32 * s + 8 * gq];
  __syncthreads();   // all waves done with K/V reads -> bufA/bufB usable

  if constexpr (PRE) stage9(wsw + WPROJ, bufA, wv, lane);   // the single exposed stage
  __syncthreads();

  if constexpr (PRE) stage9(wsw + WPROJ + 9 * 512, bufB, wv, lane);
  float y[6][4];
  __builtin_amdgcn_s_setprio(1);
  #pragma unroll
  for (int nt = 0; nt < 3; ++nt) {
    f32x4 acc = zf;
    #pragma unroll
    for (int s = 0; s < 3; ++s) {
      short8 wfr = PRE ? *(const short8*)&bufA[(nt * 3 + s) * 512 + lane * 8]
                       : ldw8(proj_w + (size_t)(16 * nt + ln) * 96 + 32 * s + 8 * gq);
      acc = __builtin_amdgcn_mfma_f32_16x16x32_bf16(wfr, ao[s], acc, 0, 0, 0);
    }
    float4 pb = *(const float4*)&proj_b[16 * nt + 4 * gq];
    y[nt][0] = acc[0] + pb.x + xraw[nt][0];
    y[nt][1] = acc[1] + pb.y + xraw[nt][1];
    y[nt][2] = acc[2] + pb.z + xraw[nt][2];
    y[nt][3] = acc[3] + pb.w + xraw[nt][3];
  }
  __builtin_amdgcn_s_setprio(0);
  __syncthreads();   // bufB landed; bufA reads done

  if constexpr (PRE) stage9(wsw + WFC1, bufA, wv, lane);
  __builtin_amdgcn_s_setprio(1);
  #pragma unroll
  for (int nt = 3; nt < 6; ++nt) {
    f32x4 acc = zf;
    #pragma unroll
    for (int s = 0; s < 3; ++s) {
      short8 wfr = PRE ? *(const short8*)&bufB[((nt - 3) * 3 + s) * 512 + lane * 8]
                       : ldw8(proj_w + (size_t)(16 * nt + ln) * 96 + 32 * s + 8 * gq);
      acc = __builtin_amdgcn_mfma_f32_16x16x32_bf16(wfr, ao[s], acc, 0, 0, 0);
    }
    float4 pb = *(const float4*)&proj_b[16 * nt + 4 * gq];
    y[nt][0] = acc[0] + pb.x + xraw[nt][0];
    y[nt][1] = acc[1] + pb.y + xraw[nt][1];
    y[nt][2] = acc[2] + pb.z + xraw[nt][2];
    y[nt][3] = acc[3] + pb.w + xraw[nt][3];
  }
  __builtin_amdgcn_s_setprio(0);
  {
    float s1 = 0.f, s2 = 0.f;
    #pragma unroll
    for (int nt = 0; nt < 6; ++nt)
      #pragma unroll
      for (int r = 0; r < 4; ++r) { s1 += y[nt][r]; s2 += y[nt][r] * y[nt][r]; }
    s1 += __shfl_xor(s1, 16, 64); s1 += __shfl_xor(s1, 32, 64);
    s2 += __shfl_xor(s2, 16, 64); s2 += __shfl_xor(s2, 32, 64);
    float mean = s1 * (1.f / 96.f);
    float inv  = rsqrtf(s2 * (1.f / 96.f) - mean * mean + 1e-5f);
    #pragma unroll
    for (int nt = 0; nt < 6; ++nt) {
      float4 g4 = *(const float4*)&n2g[16 * nt + 4 * gq];
      float4 b4 = *(const float4*)&n2b[16 * nt + 4 * gq];
      st4(&pool[OFF_Q + qq * SR + 16 * nt + 4 * gq],
          (y[nt][0] - mean) * inv * g4.x + b4.x,
          (y[nt][1] - mean) * inv * g4.y + b4.y,
          (y[nt][2] - mean) * inv * g4.z + b4.z,
          (y[nt][3] - mean) * inv * g4.w + b4.w);
    }
  }
  short8 ay[3];
  #pragma unroll
  for (int s = 0; s < 3; ++s)
    ay[s] = *(const short8*)&pool[OFF_Q + qq * SR + 32 * s + 8 * gq];
  __syncthreads();   // bufA (fc1.c0.h0) landed; bufB reads done

  // ---- stage 5: MLP, 4 chunks x 4 pipelined half-stages ----
  f32x4 accO[6] = {zf, zf, zf, zf, zf, zf};
  for (int cn = 0; cn < 4; ++cn) {
    // (a) stage fc1.cn.h1 -> bufB || fc1 nt 0..2 from bufA
    if constexpr (PRE) stage9(wsw + WFC1 + (cn * 18 + 9) * 512, bufB, wv, lane);
    __builtin_amdgcn_s_setprio(1);
    #pragma unroll
    for (int nt = 0; nt < 3; ++nt) {
      f32x4 acc = zf;
      #pragma unroll
      for (int s = 0; s < 3; ++s) {
        short8 wfr = PRE ? *(const short8*)&bufA[(nt * 3 + s) * 512 + lane * 8]
                         : ldw8(fc1_w + (size_t)(96 * cn + 16 * nt + ln) * 96 + 32 * s + 8 * gq);
        acc = __builtin_amdgcn_mfma_f32_16x16x32_bf16(wfr, ay[s], acc, 0, 0, 0);
      }
      float4 b1 = *(const float4*)&fc1_b[96 * cn + 16 * nt + 4 * gq];
      st4(&pool[OFF_X + qq * SR + 16 * nt + 4 * gq],
          gelu(acc[0] + b1.x), gelu(acc[1] + b1.y),
          gelu(acc[2] + b1.z), gelu(acc[3] + b1.w));
    }
    __builtin_amdgcn_s_setprio(0);
    __syncthreads();
    // (b) stage fc2.cn.h0 -> bufA || fc1 nt 3..5 from bufB; then ah frags (own row)
    if constexpr (PRE) stage9(wsw + WFC2 + (cn * 18) * 512, bufA, wv, lane);
    __builtin_amdgcn_s_setprio(1);
    #pragma unroll
    for (int nt = 3; nt < 6; ++nt) {
      f32x4 acc = zf;
      #pragma unroll
      for (int s = 0; s < 3; ++s) {
        short8 wfr = PRE ? *(const short8*)&bufB[((nt - 3) * 3 + s) * 512 + lane * 8]
                         : ldw8(fc1_w + (size_t)(96 * cn + 16 * nt + ln) * 96 + 32 * s + 8 * gq);
        acc = __builtin_amdgcn_mfma_f32_16x16x32_bf16(wfr, ay[s], acc, 0, 0, 0);
      }
      float4 b1 = *(const float4*)&fc1_b[96 * cn + 16 * nt + 4 * gq];
      st4(&pool[OFF_X + qq * SR + 16 * nt + 4 * gq],
          gelu(acc[0] + b1.x), gelu(acc[1] + b1.y),
          gelu(acc[2] + b1.z), gelu(acc[3] + b1.w));
    }
    __builtin_amdgcn_s_setprio(0);
    short8 ah[3];
    #pragma unroll
    for (int s = 0; s < 3; ++s)
      ah[s] = *(const short8*)&pool[OFF_X + qq * SR + 32 * s + 8 * gq];
    __syncthreads();
    // (c) stage fc2.cn.h1 -> bufB || fc2 nt 0..2 from bufA
    if constexpr (PRE) stage9(wsw + WFC2 + (cn * 18 + 9) * 512, bufB, wv, lane);
    __builtin_amdgcn_s_setprio(1);
    #pragma unroll
    for (int nt = 0; nt < 3; ++nt) {
      #pragma unroll
      for (int s = 0; s < 3; ++s) {
        short8 wfr = PRE ? *(const short8*)&bufA[(nt * 3 + s) * 512 + lane * 8]
                         : ldw8(fc2_w + (size_t)(16 * nt + ln) * 384 + 96 * cn + 32 * s + 8 * gq);
        accO[nt] = __builtin_amdgcn_mfma_f32_16x16x32_bf16(wfr, ah[s], accO[nt], 0, 0, 0);
      }
    }
    __builtin_amdgcn_s_setprio(0);
    __syncthreads();
    // (d) stage fc1.(cn+1).h0 -> bufA || fc2 nt 3..5 from bufB
    if constexpr (PRE) { if (cn < 3) stage9(wsw + WFC1 + ((cn + 1) * 18) * 512, bufA, wv, lane); }
    __builtin_amdgcn_s_setprio(1);
    #pragma unroll
    for (int nt = 3; nt < 6; ++nt) {
      #pragma unroll
      for (int s = 0; s < 3; ++s) {
        short8 wfr = PRE ? *(const short8*)&bufB[((nt - 3) * 3 + s) * 512 + lane * 8]
                         : ldw8(fc2_w + (size_t)(16 * nt + ln) * 384 + 96 * cn + 32 * s + 8 * gq);
        accO[nt] = __builtin_amdgcn_mfma_f32_16x16x32_bf16(wfr, ah[s], accO[nt], 0, 0, 0);
      }
    }
    __builtin_amdgcn_s_setprio(0);
    __syncthreads();
  }

  // ---- stage 6: out = y + mlp + fc2_b (float4 stores) ----
  if (qq < 49) {
    float* dst = out + obase;
    #pragma unroll
    for (int nt = 0; nt < 6; ++nt) {
      float4 fb = *(const float4*)&fc2_b[16 * nt + 4 * gq];
      float4 v;
      v.x = y[nt][0] + accO[nt][0] + fb.x;
      v.y = y[nt][1] + accO[nt][1] + fb.y;
      v.z = y[nt][2] + accO[nt][2] + fb.z;
      v.w = y[nt][3] + accO[nt][3] + fb.w;
      *(float4*)&dst[16 * nt + 4 * gq] = v;
    }
  }
}

extern "C" void kernel_launch(void* const* d_in, const int* in_sizes, int n_in,
                              void* d_out, int out_size, void* d_ws, size_t ws_size,
                              hipStream_t stream) {
  const float* x         = (const float*)d_in[0];
  const float* attn_mask = (const float*)d_in[1];
  const int*   rel_index = (const int*)  d_in[2];
  const float* n1g       = (const float*)d_in[3];
  const float* n1b       = (const float*)d_in[4];
  const float* qkv_w     = (const float*)d_in[5];
  const float* qkv_b     = (const float*)d_in[6];
  const float* rel_tab   = (const float*)d_in[7];
  const float* proj_w    = (const float*)d_in[8];
  const float* proj_b    = (const float*)d_in[9];
  const float* n2g       = (const float*)d_in[10];
  const float* n2b       = (const float*)d_in[11];
  const float* fc1_w     = (const float*)d_in[12];
  const float* fc1_b     = (const float*)d_in[13];
  const float* fc2_w     = (const float*)d_in[14];
  const float* fc2_b     = (const float*)d_in[15];
  float* out = (float*)d_out;

  const int B = in_sizes[0] / (HW * HW * 96);
  const bool m1 = ws_size >= WS_M1;
  const bool m2 = ws_size >= WS_M2;
  short* ws    = (short*)d_ws;
  float* bias3 = (float*)((char*)d_ws + WS_M1);

  if (m1)
    cvt_weights<<<(WTOT + 255) / 256, 256, 0, stream>>>(qkv_w, proj_w, fc1_w, fc2_w, ws);
  if (m2)
    prep_bias<<<(BIASN + 255) / 256, 256, 0, stream>>>(attn_mask, rel_index, rel_tab, bias3);

  if (m2)
    swin_mfma_kernel<2><<<B * 64, 256, 0, stream>>>(
        x, attn_mask, rel_index, n1g, n1b, qkv_w, qkv_b, rel_tab, proj_w, proj_b,
        n2g, n2b, fc1_w, fc1_b, fc2_w, fc2_b, (const short*)ws, (const float*)bias3, out);
  else if (m1)
    swin_mfma_kernel<1><<<B * 64, 256, 0, stream>>>(
        x, attn_mask, rel_index, n1g, n1b, qkv_w, qkv_b, rel_tab, proj_w, proj_b,
        n2g, n2b, fc1_w, fc1_b, fc2_w, fc2_b, (const short*)ws, (const float*)nullptr, out);
  else
    swin_mfma_kernel<0><<<B * 64, 256, 0, stream>>>(
        x, attn_mask, rel_index, n1g, n1b, qkv_w, qkv_b, rel_tab, proj_w, proj_b,
        n2g, n2b, fc1_w, fc1_b, fc2_w, fc2_b, (const short*)nullptr, (const float*)nullptr, out);
}